// Round 1
// baseline (272.681 us; speedup 1.0000x reference)
//
#include <hip/hip_runtime.h>

namespace {

constexpr int T = 32, H = 56, W = 56;
constexpr int HW = H * W;
constexpr int THW = T * HW;
constexpr int GROUPS = H * (W / 2);   // 1568 two-pixel groups per (b,c) plane-stack

template <int N> struct ic { static constexpr int value = N; };

__device__ __forceinline__ float sigm(float x) {
    // 1/(1+e^-x); fast native exp + rcp (rel err ~1e-6, threshold is 1.9e-2)
    float e = __expf(-x);
    return __builtin_amdgcn_rcpf(1.0f + e);
}

__global__ __launch_bounds__(64, 3)
void tts_fused(const float* __restrict__ x,
               const float* __restrict__ w1, const float* __restrict__ b1,
               const float* __restrict__ w2, const float* __restrict__ b2,
               const float* __restrict__ w3, const float* __restrict__ b3,
               const float* __restrict__ wm,
               float* __restrict__ out) {
    // blockIdx.y = (b*64 + c)  -> block-uniform so weight loads stay scalar.
    // blockIdx.x * 64 + tid    -> linear 2-pixel group within the 56x56 plane.
    const int g = blockIdx.x * 64 + threadIdx.x;
    if (g >= GROUPS) return;          // no barriers anywhere -> safe early exit
    const int bc = blockIdx.y;
    const int h  = g / 28;            // 0..55
    const int wq = g - h * 28;        // 0..27
    const int w0 = wq << 1;           // 2 pixels per thread, 8B-aligned

    const float* __restrict__ xbc = x + (size_t)bc * THW;
    float* __restrict__ obc       = out + (size_t)bc * THW;
    const int c = bc & 63;
    const float* __restrict__ wa = w1 + c * 27;  // [kt*9 + kh*3 + kw]
    const float* __restrict__ wb = w2 + c * 27;
    const float* __restrict__ wc = w3 + c * 27;
    const float bias1 = b1[c], bias2 = b2[c], bias3 = b3[c];
    const float W0 = wm[0], W1 = wm[1], W2 = wm[2];
    const float goff = 0.5f * (W0 + W1 + W2);

    const bool vtop = (h >= 1), vbot = (h <= H - 2);
    const bool vl = (wq > 0), vr = (wq < 27);
    const int boff = h * W + w0;

    // register cache: 7 planes (t-3..t+3, slot = plane mod 7) x 3 rows x 4 cols (w0-1..w0+2)
    float cc[7][3][4];
    // lag-diff shift registers per pixel
    float p1[2], p2a[2], p2b[2], p3a[2], p3b[2], p3c[2];
#pragma unroll
    for (int p = 0; p < 2; ++p) {
        p1[p] = 0.f; p2a[p] = 0.f; p2b[p] = 0.f;
        p3a[p] = 0.f; p3b[p] = 0.f; p3c[p] = 0.f;
    }

    auto zero_plane = [&](auto Sc) {
        constexpr int s = decltype(Sc)::value;
#pragma unroll
        for (int r = 0; r < 3; ++r)
#pragma unroll
            for (int j = 0; j < 4; ++j) cc[s][r][j] = 0.f;
    };

    auto load_plane = [&](auto Sc, int tp) {
        constexpr int s = decltype(Sc)::value;
        const float* pp = xbc + tp * HW + boff;
#pragma unroll
        for (int r = 0; r < 3; ++r) {
            const bool vrow = (r == 0) ? vtop : ((r == 2) ? vbot : true);
            const float* rp = pp + (r - 1) * W;
            if (vrow) {
                const float2 m = *(const float2*)rp;      // aligned: offset % 2 == 0
                cc[s][r][1] = m.x; cc[s][r][2] = m.y;
                cc[s][r][0] = vl ? rp[-1] : 0.f;
                cc[s][r][3] = vr ? rp[2]  : 0.f;
            } else {
#pragma unroll
                for (int j = 0; j < 4; ++j) cc[s][r][j] = 0.f;
            }
        }
    };

    auto conv9 = [&](float (&acc)[2], auto Sc, const float* __restrict__ wp) {
        constexpr int s = decltype(Sc)::value;
#pragma unroll
        for (int r = 0; r < 3; ++r)
#pragma unroll
            for (int kw = 0; kw < 3; ++kw) {
                const float wg = wp[r * 3 + kw];
#pragma unroll
                for (int p = 0; p < 2; ++p)
                    acc[p] = fmaf(cc[s][r][p + kw], wg, acc[p]);
            }
    };

    // prologue: planes -3..-1 are zero (slots 4,5,6); planes 0..2 loaded (slots 0,1,2)
    zero_plane(ic<4>{}); zero_plane(ic<5>{}); zero_plane(ic<6>{});
    load_plane(ic<0>{}, 0); load_plane(ic<1>{}, 1); load_plane(ic<2>{}, 2);

    auto step = [&](int t, auto Uc) {   // requires t % 7 == Uc
        constexpr int u = decltype(Uc)::value;
        constexpr int snew = (u + 3) % 7;               // slot of plane t+3
        if (t + 3 < T) load_plane(ic<snew>{}, t + 3);
        else           zero_plane(ic<snew>{});

        float a1[2], a2[2], a3[2];
#pragma unroll
        for (int p = 0; p < 2; ++p) { a1[p] = bias1; a2[p] = bias2; a3[p] = bias3; }

        conv9(a1, ic<(u + 6) % 7>{}, wa);       // plane t-1
        conv9(a1, ic<u>{},           wa + 9);   // plane t
        conv9(a1, ic<(u + 1) % 7>{}, wa + 18);  // plane t+1
        conv9(a2, ic<(u + 5) % 7>{}, wb);       // plane t-2
        conv9(a2, ic<u>{},           wb + 9);   // plane t
        conv9(a2, ic<(u + 2) % 7>{}, wb + 18);  // plane t+2
        conv9(a3, ic<(u + 4) % 7>{}, wc);       // plane t-3
        conv9(a3, ic<u>{},           wc + 9);   // plane t
        conv9(a3, ic<(u + 3) % 7>{}, wc + 18);  // plane t+3 (freshly loaded) LAST

        float2 ov;
        float* ovp = (float*)&ov;
#pragma unroll
        for (int p = 0; p < 2; ++p) {
            const float y1 = a1[p], y2 = a2[p], y3 = a3[p];
            const float d1 = (t >= 1) ? y1 - p1[p]  : y1;
            const float d2 = (t >= 2) ? y2 - p2b[p] : y2;
            const float d3 = (t >= 3) ? y3 - p3c[p] : y3;
            p1[p]  = y1;
            p2b[p] = p2a[p]; p2a[p] = y2;
            p3c[p] = p3b[p]; p3b[p] = p3a[p]; p3a[p] = y3;
            const float gte = fmaf(sigm(d1), W0,
                             fmaf(sigm(d2), W1,
                             fmaf(sigm(d3), W2, -goff)));
            ovp[p] = cc[u][1][p + 1] * gte;     // x at (t,h,w0+p) from register cache
        }
        *(float2*)(obc + t * HW + boff) = ov;
    };

#pragma unroll 1
    for (int tb = 0; tb <= T - 7; tb += 7) {    // tb = 0,7,14,21  (tb % 7 == 0)
        step(tb + 0, ic<0>{}); step(tb + 1, ic<1>{}); step(tb + 2, ic<2>{});
        step(tb + 3, ic<3>{}); step(tb + 4, ic<4>{}); step(tb + 5, ic<5>{});
        step(tb + 6, ic<6>{});
    }
    // remainder: t = 28..31 (28 % 7 == 0)
    step(28, ic<0>{}); step(29, ic<1>{}); step(30, ic<2>{}); step(31, ic<3>{});
}

}  // namespace

extern "C" void kernel_launch(void* const* d_in, const int* in_sizes, int n_in,
                              void* d_out, int out_size, void* d_ws, size_t ws_size,
                              hipStream_t stream) {
    (void)in_sizes; (void)n_in; (void)d_ws; (void)ws_size; (void)out_size;
    const float* x  = (const float*)d_in[0];
    const float* w1 = (const float*)d_in[1];
    const float* b1 = (const float*)d_in[2];
    const float* w2 = (const float*)d_in[3];
    const float* b2 = (const float*)d_in[4];
    const float* w3 = (const float*)d_in[5];
    const float* b3 = (const float*)d_in[6];
    const float* wm = (const float*)d_in[7];
    float* out = (float*)d_out;

    // grid: x = ceil(1568 groups / 64), y = 256 (b,c) pairs; block: one wave (64 threads).
    // 1-wave blocks give the scheduler perfect packing granularity; bc in blockIdx.y
    // keeps weight/bias loads block-uniform -> scalar (s_load) path.
    tts_fused<<<dim3((GROUPS + 63) / 64, 256), dim3(64), 0, stream>>>(
        x, w1, b1, w2, b2, w3, b3, wm, out);
}